// Round 1
// baseline (82.259 us; speedup 1.0000x reference)
//
#include <hip/hip_runtime.h>
#include <hip/hip_bf16.h>

typedef __bf16 bf16x8 __attribute__((ext_vector_type(8)));
typedef float  f32x4  __attribute__((ext_vector_type(4)));

#define NROWS 8192
#define DIM   128
#define NB    64            // 8192 / 128 row-blocks
#define JOBS_PER_MAT 2080   // 64*65/2 upper-tri incl diag

__device__ __forceinline__ float waveReduceSum(float v) {
    for (int off = 32; off; off >>= 1) v += __shfl_xor(v, off, 64);
    return v;
}

// ---------------------------------------------------------------------------
// Kernel 1: normalize rows of users & pos_items, compute align partials,
// emit bf16 copies of the normalized matrices.
// 2048 blocks x 256 threads; each wave handles one row (both matrices).
// ---------------------------------------------------------------------------
__global__ __launch_bounds__(256) void prep_kernel(
    const float* __restrict__ users, const float* __restrict__ pos,
    __bf16* __restrict__ Uh, __bf16* __restrict__ Ph,
    double* __restrict__ alignPart)
{
    const int tid  = threadIdx.x;
    const int lane = tid & 63;
    const int wid  = tid >> 6;
    const int r    = blockIdx.x * 4 + wid;

    const float2 u2 = ((const float2*)users)[r * 64 + lane];
    const float2 p2 = ((const float2*)pos )[r * 64 + lane];

    const float su = waveReduceSum(u2.x * u2.x + u2.y * u2.y);
    const float sp = waveReduceSum(p2.x * p2.x + p2.y * p2.y);
    const float nu  = fmaxf(sqrtf(su), 1e-12f);
    const float npp = fmaxf(sqrtf(sp), 1e-12f);

    const float unx = u2.x / nu,  uny = u2.y / nu;
    const float pnx = p2.x / npp, pny = p2.y / npp;

    union { __bf16 h[2]; unsigned int w; } cu, cp;
    cu.h[0] = (__bf16)unx; cu.h[1] = (__bf16)uny;
    cp.h[0] = (__bf16)pnx; cp.h[1] = (__bf16)pny;
    ((unsigned int*)Uh)[r * 64 + lane] = cu.w;
    ((unsigned int*)Ph)[r * 64 + lane] = cp.w;

    const float dx = unx - pnx, dy = uny - pny;
    const float al = waveReduceSum(dx * dx + dy * dy);

    __shared__ float wsum[4];
    if (lane == 0) wsum[wid] = al;
    __syncthreads();
    if (tid == 0)
        alignPart[blockIdx.x] = (double)wsum[0] + (double)wsum[1]
                              + (double)wsum[2] + (double)wsum[3];
}

// ---------------------------------------------------------------------------
// Kernel 2: per (matrix, bi<=bj) 128x128 tile of G = Xn * Xn^T,
// accumulate sum of exp(min(4*dot-4, 0)); off-diagonal tiles weighted x2.
// 256 threads = 4 waves (2x2), each wave owns a 64x64 sub-tile (4x4 MFMA frags).
// ---------------------------------------------------------------------------
__global__ __launch_bounds__(256) void gram_kernel(
    const __bf16* __restrict__ Uh, const __bf16* __restrict__ Ph,
    double* __restrict__ Spart)
{
    const int bid = blockIdx.x;
    const int mat = bid / JOBS_PER_MAT;
    int t = bid - mat * JOBS_PER_MAT;
    int bi = 0;
    while (t >= NB - bi) { t -= NB - bi; ++bi; }
    const int bj = bi + t;

    const __bf16* __restrict__ X = mat ? Ph : Uh;

    const int tid  = threadIdx.x;
    const int lane = tid & 63;
    const int wid  = tid >> 6;
    const int wm = wid >> 1, wn = wid & 1;
    const int lr = lane & 15;          // row within 16-row fragment
    const int lk = (lane >> 4) * 8;    // k-offset of this lane's 8 elements

    const int arow0 = bi * 128 + wm * 64 + lr;
    const int brow0 = bj * 128 + wn * 64 + lr;

    f32x4 acc[4][4];
#pragma unroll
    for (int mi = 0; mi < 4; ++mi)
#pragma unroll
        for (int ni = 0; ni < 4; ++ni)
            acc[mi][ni] = (f32x4){0.f, 0.f, 0.f, 0.f};

#pragma unroll
    for (int ks = 0; ks < 4; ++ks) {
        const int kb = ks * 32 + lk;
        bf16x8 a[4], b[4];
#pragma unroll
        for (int mi = 0; mi < 4; ++mi)
            a[mi] = *reinterpret_cast<const bf16x8*>(X + (size_t)(arow0 + mi * 16) * DIM + kb);
#pragma unroll
        for (int ni = 0; ni < 4; ++ni)
            b[ni] = *reinterpret_cast<const bf16x8*>(X + (size_t)(brow0 + ni * 16) * DIM + kb);
#pragma unroll
        for (int mi = 0; mi < 4; ++mi)
#pragma unroll
            for (int ni = 0; ni < 4; ++ni)
                acc[mi][ni] = __builtin_amdgcn_mfma_f32_16x16x32_bf16(
                    a[mi], b[ni], acc[mi][ni], 0, 0, 0);
    }

    float s = 0.f;
#pragma unroll
    for (int mi = 0; mi < 4; ++mi)
#pragma unroll
        for (int ni = 0; ni < 4; ++ni)
#pragma unroll
            for (int e = 0; e < 4; ++e)
                s += __expf(fminf(4.0f * acc[mi][ni][e] - 4.0f, 0.0f));

    s = waveReduceSum(s);
    __shared__ float wsum[4];
    if (lane == 0) wsum[wid] = s;
    __syncthreads();
    if (tid == 0) {
        double bs = (double)wsum[0] + (double)wsum[1]
                  + (double)wsum[2] + (double)wsum[3];
        if (bi != bj) bs *= 2.0;     // off-diagonal block counts twice in S_full
        Spart[bid] = bs;
    }
}

// ---------------------------------------------------------------------------
// Kernel 3: final reduction + loss formula. One block of 256 threads.
// ---------------------------------------------------------------------------
__global__ __launch_bounds__(256) void finalize_kernel(
    const double* __restrict__ alignPart, const double* __restrict__ Spart,
    float* __restrict__ out)
{
    const int tid = threadIdx.x;
    double a = 0.0, su = 0.0, sp = 0.0;
    for (int i = tid; i < 2048; i += 256) a += alignPart[i];
    for (int i = tid; i < JOBS_PER_MAT; i += 256) su += Spart[i];
    for (int i = tid; i < JOBS_PER_MAT; i += 256) sp += Spart[JOBS_PER_MAT + i];

    for (int off = 32; off; off >>= 1) {
        a  += __shfl_xor(a,  off, 64);
        su += __shfl_xor(su, off, 64);
        sp += __shfl_xor(sp, off, 64);
    }
    __shared__ double sh[3][4];
    const int lane = tid & 63, wid = tid >> 6;
    if (lane == 0) { sh[0][wid] = a; sh[1][wid] = su; sh[2][wid] = sp; }
    __syncthreads();
    if (tid == 0) {
        const double A  = sh[0][0] + sh[0][1] + sh[0][2] + sh[0][3];
        const double SU = sh[1][0] + sh[1][1] + sh[1][2] + sh[1][3];
        const double SP = sh[2][0] + sh[2][1] + sh[2][2] + sh[2][3];
        const double Nd = 8192.0;
        const double npairs = Nd * (Nd - 1.0) * 0.5;
        const double align = A / Nd;
        const double mu = (SU - Nd) * 0.5 / npairs;   // mean over i<j pairs
        const double mp = (SP - Nd) * 0.5 / npairs;
        const double uniform = 0.25 * (log(mu) + log(mp));
        out[0] = (float)((align + uniform) / 8192.0);
    }
}

// ---------------------------------------------------------------------------
extern "C" void kernel_launch(void* const* d_in, const int* in_sizes, int n_in,
                              void* d_out, int out_size, void* d_ws, size_t ws_size,
                              hipStream_t stream)
{
    const float* users = (const float*)d_in[0];
    const float* pos   = (const float*)d_in[1];
    // d_in[2] (neg_items) intentionally unused, matching the reference.
    float* out = (float*)d_out;

    char* ws = (char*)d_ws;
    __bf16* Uh = (__bf16*)ws;                         // 8192*128*2 = 2 MiB
    __bf16* Ph = (__bf16*)(ws + 2097152);             // 2 MiB
    double* alignPart = (double*)(ws + 4194304);      // 2048 doubles
    double* Spart     = (double*)(ws + 4194304 + 16384); // 4160 doubles

    hipLaunchKernelGGL(prep_kernel, dim3(2048), dim3(256), 0, stream,
                       users, pos, Uh, Ph, alignPart);
    hipLaunchKernelGGL(gram_kernel, dim3(2 * JOBS_PER_MAT), dim3(256), 0, stream,
                       Uh, Ph, Spart);
    hipLaunchKernelGGL(finalize_kernel, dim3(1), dim3(256), 0, stream,
                       alignPart, Spart, out);
}

// Round 2
// 55.448 us; speedup vs baseline: 1.4836x; 1.4836x over previous
//
#include <hip/hip_runtime.h>
#include <hip/hip_bf16.h>

typedef __bf16 bf16x8 __attribute__((ext_vector_type(8)));
typedef float  f32x4  __attribute__((ext_vector_type(4)));

#define NROWS 8192
#define DIM   128
#define NB    64            // 8192 / 128 row-blocks
#define JOBS_PER_MAT 2080   // 64*65/2 upper-tri incl diag

__device__ __forceinline__ float waveReduceSum(float v) {
    for (int off = 32; off; off >>= 1) v += __shfl_xor(v, off, 64);
    return v;
}

// async global->LDS, 16B per lane; lds dest must be wave-uniform base (+lane*16 by HW)
__device__ __forceinline__ void gload16(const void* g, void* l) {
    __builtin_amdgcn_global_load_lds(
        (const __attribute__((address_space(1))) unsigned int*)(uintptr_t)g,
        (__attribute__((address_space(3))) unsigned int*)(uintptr_t)l,
        16, 0, 0);
}

// jobs before row-block b in the upper-tri enumeration
__device__ __forceinline__ int tri(int b) { return b * NB - (b * (b - 1)) / 2; }

// ---------------------------------------------------------------------------
// Kernel 1: normalize rows, compute align partials, emit bf16 copies.
// ---------------------------------------------------------------------------
__global__ __launch_bounds__(256) void prep_kernel(
    const float* __restrict__ users, const float* __restrict__ pos,
    __bf16* __restrict__ Uh, __bf16* __restrict__ Ph,
    double* __restrict__ alignPart)
{
    const int tid  = threadIdx.x;
    const int lane = tid & 63;
    const int wid  = tid >> 6;
    const int r    = blockIdx.x * 4 + wid;

    const float2 u2 = ((const float2*)users)[r * 64 + lane];
    const float2 p2 = ((const float2*)pos )[r * 64 + lane];

    const float su = waveReduceSum(u2.x * u2.x + u2.y * u2.y);
    const float sp = waveReduceSum(p2.x * p2.x + p2.y * p2.y);
    const float nu  = fmaxf(sqrtf(su), 1e-12f);
    const float npp = fmaxf(sqrtf(sp), 1e-12f);

    const float unx = u2.x / nu,  uny = u2.y / nu;
    const float pnx = p2.x / npp, pny = p2.y / npp;

    union { __bf16 h[2]; unsigned int w; } cu, cp;
    cu.h[0] = (__bf16)unx; cu.h[1] = (__bf16)uny;
    cp.h[0] = (__bf16)pnx; cp.h[1] = (__bf16)pny;
    ((unsigned int*)Uh)[r * 64 + lane] = cu.w;
    ((unsigned int*)Ph)[r * 64 + lane] = cp.w;

    const float dx = unx - pnx, dy = uny - pny;
    const float al = waveReduceSum(dx * dx + dy * dy);

    __shared__ float wsum[4];
    if (lane == 0) wsum[wid] = al;
    __syncthreads();
    if (tid == 0)
        alignPart[blockIdx.x] = (double)wsum[0] + (double)wsum[1]
                              + (double)wsum[2] + (double)wsum[3];
}

// ---------------------------------------------------------------------------
// Kernel 2: 128x128 tile of G = Xn*Xn^T per block (bi<=bj upper-tri tiles,
// off-diag weighted x2), LDS-staged with XOR chunk swizzle.
//   LDS layout: A tile bytes [0,32K), B tile [32K,64K). Row = 256B = 16 chunks
//   of 16B. Linear LDS chunk (r, cs) holds global chunk (r, cs ^ (r&7))
//   (pre-swizzled source; global_load_lds dest is linear). Reads XOR back.
// ---------------------------------------------------------------------------
__global__ __launch_bounds__(256) void gram_kernel(
    const __bf16* __restrict__ Uh, const __bf16* __restrict__ Ph,
    double* __restrict__ Spart)
{
    __shared__ __align__(16) unsigned char smem[65536];

    const int bid = blockIdx.x;
    const int mat = bid >= JOBS_PER_MAT;
    const int t   = bid - (mat ? JOBS_PER_MAT : 0);

    // decode upper-tri (bi, bj) from t: tri(bi) <= t < tri(bi+1)
    int bi = (int)((NB + 0.5f) - sqrtf((NB + 0.5f) * (NB + 0.5f) - 2.0f * (float)t));
    if (bi > 0 && tri(bi) > t) --bi;
    if (tri(bi + 1) <= t) ++bi;
    const int bj = bi + (t - tri(bi));

    const char* __restrict__ Xb = (const char*)(mat ? Ph : Uh);

    const int tid = threadIdx.x;

    // ---- stage A (rows bi*128..+128) and B (rows bj*128..+128) into LDS ----
    {
        const int r16 = tid >> 4;            // 0..15 row within 16-row slab
        const int cs  = tid & 15;            // linear LDS chunk within row
        const int gc  = cs ^ (r16 & 7);      // pre-swizzled global chunk
        const char* gA = Xb + (size_t)(bi * 128 + r16) * 256 + gc * 16;
        const char* gB = Xb + (size_t)(bj * 128 + r16) * 256 + gc * 16;
        unsigned char* lbase = smem + (tid >> 6) * 1024;
#pragma unroll
        for (int i = 0; i < 8; ++i) {
            gload16(gA + i * 4096, lbase + i * 4096);
            gload16(gB + i * 4096, lbase + 32768 + i * 4096);
        }
    }
    __syncthreads();   // implies s_waitcnt vmcnt(0) before barrier

    // ---- MFMA from LDS ----
    const int lane = tid & 63;
    const int wid  = tid >> 6;
    const int wm = wid >> 1, wn = wid & 1;
    const int lr = lane & 15;          // row within 16-row fragment
    const int lg = lane >> 4;          // k-chunk group 0..3
    const unsigned cxor = (unsigned)(lr & 7);      // row&7 for all frag rows
    const unsigned aRow = (unsigned)(wm * 64 + lr) * 256;
    const unsigned bRow = (unsigned)(wn * 64 + lr) * 256 + 32768;

    f32x4 acc[4][4];
#pragma unroll
    for (int mi = 0; mi < 4; ++mi)
#pragma unroll
        for (int ni = 0; ni < 4; ++ni)
            acc[mi][ni] = (f32x4){0.f, 0.f, 0.f, 0.f};

#pragma unroll
    for (int ks = 0; ks < 4; ++ks) {
        const unsigned sc = (((unsigned)(ks * 4 + lg)) ^ cxor) << 4;
        bf16x8 a[4], b[4];
#pragma unroll
        for (int mi = 0; mi < 4; ++mi)
            a[mi] = *reinterpret_cast<const bf16x8*>(smem + aRow + mi * 4096 + sc);
#pragma unroll
        for (int ni = 0; ni < 4; ++ni)
            b[ni] = *reinterpret_cast<const bf16x8*>(smem + bRow + ni * 4096 + sc);
#pragma unroll
        for (int mi = 0; mi < 4; ++mi)
#pragma unroll
            for (int ni = 0; ni < 4; ++ni)
                acc[mi][ni] = __builtin_amdgcn_mfma_f32_16x16x32_bf16(
                    a[mi], b[ni], acc[mi][ni], 0, 0, 0);
    }

    // ---- exp epilogue: exp(min(4*dot-4,0)) via exp2 ----
    const float C1 = 4.0f * 1.4426950408889634f;   // 4*log2(e)
    float s0 = 0.f, s1 = 0.f, s2 = 0.f, s3 = 0.f;
#pragma unroll
    for (int mi = 0; mi < 4; ++mi)
#pragma unroll
        for (int ni = 0; ni < 4; ++ni) {
            const f32x4 v = acc[mi][ni];
            s0 += exp2f(fminf(v[0] * C1 - C1, 0.0f));
            s1 += exp2f(fminf(v[1] * C1 - C1, 0.0f));
            s2 += exp2f(fminf(v[2] * C1 - C1, 0.0f));
            s3 += exp2f(fminf(v[3] * C1 - C1, 0.0f));
        }

    float s = waveReduceSum((s0 + s1) + (s2 + s3));
    __shared__ float wsum[4];
    if (lane == 0) wsum[wid] = s;
    __syncthreads();
    if (tid == 0) {
        double bs = (double)wsum[0] + (double)wsum[1]
                  + (double)wsum[2] + (double)wsum[3];
        if (bi != bj) bs *= 2.0;     // off-diagonal tile counts twice in S_full
        Spart[bid] = bs;
    }
}

// ---------------------------------------------------------------------------
// Kernel 3: final reduction + loss formula.
// ---------------------------------------------------------------------------
__global__ __launch_bounds__(256) void finalize_kernel(
    const double* __restrict__ alignPart, const double* __restrict__ Spart,
    float* __restrict__ out)
{
    const int tid = threadIdx.x;
    double a = 0.0, su = 0.0, sp = 0.0;
    for (int i = tid; i < 2048; i += 256) a += alignPart[i];
    for (int i = tid; i < JOBS_PER_MAT; i += 256) su += Spart[i];
    for (int i = tid; i < JOBS_PER_MAT; i += 256) sp += Spart[JOBS_PER_MAT + i];

    for (int off = 32; off; off >>= 1) {
        a  += __shfl_xor(a,  off, 64);
        su += __shfl_xor(su, off, 64);
        sp += __shfl_xor(sp, off, 64);
    }
    __shared__ double sh[3][4];
    const int lane = tid & 63, wid = tid >> 6;
    if (lane == 0) { sh[0][wid] = a; sh[1][wid] = su; sh[2][wid] = sp; }
    __syncthreads();
    if (tid == 0) {
        const double A  = sh[0][0] + sh[0][1] + sh[0][2] + sh[0][3];
        const double SU = sh[1][0] + sh[1][1] + sh[1][2] + sh[1][3];
        const double SP = sh[2][0] + sh[2][1] + sh[2][2] + sh[2][3];
        const double Nd = 8192.0;
        const double npairs = Nd * (Nd - 1.0) * 0.5;
        const double align = A / Nd;
        const double mu = (SU - Nd) * 0.5 / npairs;   // mean over i<j pairs
        const double mp = (SP - Nd) * 0.5 / npairs;
        const double uniform = 0.25 * (log(mu) + log(mp));
        out[0] = (float)((align + uniform) / 8192.0);
    }
}

// ---------------------------------------------------------------------------
extern "C" void kernel_launch(void* const* d_in, const int* in_sizes, int n_in,
                              void* d_out, int out_size, void* d_ws, size_t ws_size,
                              hipStream_t stream)
{
    const float* users = (const float*)d_in[0];
    const float* pos   = (const float*)d_in[1];
    // d_in[2] (neg_items) intentionally unused, matching the reference.
    float* out = (float*)d_out;

    char* ws = (char*)d_ws;
    __bf16* Uh = (__bf16*)ws;                         // 2 MiB
    __bf16* Ph = (__bf16*)(ws + 2097152);             // 2 MiB
    double* alignPart = (double*)(ws + 4194304);      // 2048 doubles
    double* Spart     = (double*)(ws + 4194304 + 16384); // 4160 doubles

    hipLaunchKernelGGL(prep_kernel, dim3(2048), dim3(256), 0, stream,
                       users, pos, Uh, Ph, alignPart);
    hipLaunchKernelGGL(gram_kernel, dim3(2 * JOBS_PER_MAT), dim3(256), 0, stream,
                       Uh, Ph, Spart);
    hipLaunchKernelGGL(finalize_kernel, dim3(1), dim3(256), 0, stream,
                       alignPart, Spart, out);
}

// Round 4
// 46.145 us; speedup vs baseline: 1.7826x; 1.2016x over previous
//
#include <hip/hip_runtime.h>
#include <hip/hip_bf16.h>

typedef __bf16 bf16x8 __attribute__((ext_vector_type(8)));
typedef float  f32x4  __attribute__((ext_vector_type(4)));

#define NROWS 8192
#define DIM   128
#define NB    64            // 8192 / 128 row-blocks
#define JOBS_PER_MAT 2080   // 64*65/2 upper-tri incl diag

__device__ __forceinline__ float waveReduceSum(float v) {
    for (int off = 32; off; off >>= 1) v += __shfl_xor(v, off, 64);
    return v;
}

// native v_exp_f32 (2^x)
__device__ __forceinline__ float fast_exp2(float x) {
    return __builtin_amdgcn_exp2f(x);
}

// async global->LDS, 16B per lane; lds dest is wave-uniform base (+lane*16 by HW)
__device__ __forceinline__ void gload16(const void* g, void* l) {
    __builtin_amdgcn_global_load_lds(
        (const __attribute__((address_space(1))) unsigned int*)(uintptr_t)g,
        (__attribute__((address_space(3))) unsigned int*)(uintptr_t)l,
        16, 0, 0);
}

__device__ __forceinline__ int tri(int b) { return b * NB - (b * (b - 1)) / 2; }

// ---------------------------------------------------------------------------
// Kernel 1: normalize rows, compute align partials, emit bf16 copies.
// ---------------------------------------------------------------------------
__global__ __launch_bounds__(256) void prep_kernel(
    const float* __restrict__ users, const float* __restrict__ pos,
    __bf16* __restrict__ Uh, __bf16* __restrict__ Ph,
    double* __restrict__ alignPart)
{
    const int tid  = threadIdx.x;
    const int lane = tid & 63;
    const int wid  = tid >> 6;
    const int r    = blockIdx.x * 4 + wid;

    const float2 u2 = ((const float2*)users)[r * 64 + lane];
    const float2 p2 = ((const float2*)pos )[r * 64 + lane];

    const float su = waveReduceSum(u2.x * u2.x + u2.y * u2.y);
    const float sp = waveReduceSum(p2.x * p2.x + p2.y * p2.y);
    const float nu  = fmaxf(sqrtf(su), 1e-12f);
    const float npp = fmaxf(sqrtf(sp), 1e-12f);

    const float unx = u2.x / nu,  uny = u2.y / nu;
    const float pnx = p2.x / npp, pny = p2.y / npp;

    union { __bf16 h[2]; unsigned int w; } cu, cp;
    cu.h[0] = (__bf16)unx; cu.h[1] = (__bf16)uny;
    cp.h[0] = (__bf16)pnx; cp.h[1] = (__bf16)pny;
    ((unsigned int*)Uh)[r * 64 + lane] = cu.w;
    ((unsigned int*)Ph)[r * 64 + lane] = cp.w;

    const float dx = unx - pnx, dy = uny - pny;
    const float al = waveReduceSum(dx * dx + dy * dy);

    __shared__ float wsum[4];
    if (lane == 0) wsum[wid] = al;
    __syncthreads();
    if (tid == 0)
        alignPart[blockIdx.x] = (double)wsum[0] + (double)wsum[1]
                              + (double)wsum[2] + (double)wsum[3];
}

// ---------------------------------------------------------------------------
// Kernel 2: 128x128 tile of G = Xn*Xn^T per block, K-half double-buffered.
//   LDS: buf p (p=0,1) at p*32768: A[128][64]bf16 [0,16K) + B[128][64] [16K,32K).
//   Rows are 128B = 8 chunks of 16B. LDS(r,c) holds global chunk c^(r&7) of
//   the K-half window (pre-swizzled global source; linear gload_lds dest).
// ---------------------------------------------------------------------------
__global__ __launch_bounds__(256) void gram_kernel(
    const __bf16* __restrict__ Uh, const __bf16* __restrict__ Ph,
    double* __restrict__ Spart)
{
    __shared__ __align__(16) unsigned char smem[65536];

    const int bid = blockIdx.x;
    const int mat = bid >= JOBS_PER_MAT;
    const int t   = bid - (mat ? JOBS_PER_MAT : 0);

    int bi = (int)((NB + 0.5f) - sqrtf((NB + 0.5f) * (NB + 0.5f) - 2.0f * (float)t));
    if (bi > 0 && tri(bi) > t) --bi;
    if (tri(bi + 1) <= t) ++bi;
    const int bj = bi + (t - tri(bi));

    const char* __restrict__ Xb = (const char*)(mat ? Ph : Uh);

    const int tid  = threadIdx.x;
    const int lane = tid & 63;
    const int w    = tid >> 6;

    // ---- staging addresses (constant per thread except half/buf) ----
    const int r0 = w * 32 + (lane >> 3);          // LDS row for i=0
    const int gc = (lane & 7) ^ (r0 & 7);         // pre-swizzled global chunk
    const char* gA0 = Xb + (size_t)(bi * 128 + r0) * 256 + gc * 16;
    const char* gB0 = Xb + (size_t)(bj * 128 + r0) * 256 + gc * 16;
    unsigned char* lA0 = smem + w * 4096;         // + p*32768 ; B at +16384

#define STAGE(p, h)                                                        \
    {                                                                      \
        const int hb = (h) * 128;                                          \
        unsigned char* la = lA0 + (p) * 32768;                             \
        _Pragma("unroll")                                                  \
        for (int i = 0; i < 4; ++i) {                                      \
            gload16(gA0 + hb + i * 2048, la + i * 1024);                   \
            gload16(gB0 + hb + i * 2048, la + 16384 + i * 1024);           \
        }                                                                  \
    }

    // ---- fragment read geometry ----
    const int wm = w >> 1, wn = w & 1;
    const int lr = lane & 15;
    const int lg = lane >> 4;
    const unsigned cxor = (unsigned)(lr & 7);
    const unsigned aOff = (unsigned)(wm * 64 + lr) * 128;
    const unsigned bOff = (unsigned)(wn * 64 + lr) * 128 + 16384;

    f32x4 acc[4][4];
#pragma unroll
    for (int mi = 0; mi < 4; ++mi)
#pragma unroll
        for (int ni = 0; ni < 4; ++ni)
            acc[mi][ni] = (f32x4){0.f, 0.f, 0.f, 0.f};

#define COMPUTE(p)                                                          \
    {                                                                       \
        const unsigned base = (p) * 32768;                                  \
        _Pragma("unroll")                                                   \
        for (int ks2 = 0; ks2 < 2; ++ks2) {                                 \
            const unsigned sc = (((unsigned)(ks2 * 4 + lg)) ^ cxor) << 4;   \
            bf16x8 a[4], b[4];                                              \
            _Pragma("unroll")                                               \
            for (int mi = 0; mi < 4; ++mi)                                  \
                a[mi] = *reinterpret_cast<const bf16x8*>(                   \
                    smem + base + aOff + mi * 2048 + sc);                   \
            _Pragma("unroll")                                               \
            for (int ni = 0; ni < 4; ++ni)                                  \
                b[ni] = *reinterpret_cast<const bf16x8*>(                   \
                    smem + base + bOff + ni * 2048 + sc);                   \
            _Pragma("unroll")                                               \
            for (int mi = 0; mi < 4; ++mi)                                  \
                _Pragma("unroll")                                           \
                for (int ni = 0; ni < 4; ++ni)                              \
                    acc[mi][ni] = __builtin_amdgcn_mfma_f32_16x16x32_bf16(  \
                        a[mi], b[ni], acc[mi][ni], 0, 0, 0);                \
        }                                                                   \
    }

    STAGE(0, 0)
    __syncthreads();          // buf0 ready
    STAGE(1, 1)               // in flight under compute(buf0)
    COMPUTE(0)
    __syncthreads();          // buf1 ready; buf0 reads done
    COMPUTE(1)

    // ---- epilogue: sum exp(min(4*dot-4,0)) via native exp2 ----
    const float C1 = 4.0f * 1.4426950408889634f;   // 4*log2(e)
    float s0 = 0.f, s1 = 0.f, s2 = 0.f, s3 = 0.f;
#pragma unroll
    for (int mi = 0; mi < 4; ++mi)
#pragma unroll
        for (int ni = 0; ni < 4; ++ni) {
            const f32x4 v = acc[mi][ni];
            s0 += fast_exp2(fminf(v[0] * C1 - C1, 0.0f));
            s1 += fast_exp2(fminf(v[1] * C1 - C1, 0.0f));
            s2 += fast_exp2(fminf(v[2] * C1 - C1, 0.0f));
            s3 += fast_exp2(fminf(v[3] * C1 - C1, 0.0f));
        }

    const float s = waveReduceSum((s0 + s1) + (s2 + s3));
    float* wsum = (float*)smem;   // buf0 region; safe after both barriers
    if (lane == 0) wsum[w] = s;
    __syncthreads();
    if (tid == 0) {
        double bs = (double)wsum[0] + (double)wsum[1]
                  + (double)wsum[2] + (double)wsum[3];
        if (bi != bj) bs *= 2.0;
        Spart[bid] = bs;
    }
#undef STAGE
#undef COMPUTE
}

// ---------------------------------------------------------------------------
// Kernel 3: final reduction + loss formula. One block, 1024 threads.
// ---------------------------------------------------------------------------
__global__ __launch_bounds__(1024) void finalize_kernel(
    const double* __restrict__ alignPart, const double* __restrict__ Spart,
    float* __restrict__ out)
{
    const int tid = threadIdx.x;
    double a = 0.0, su = 0.0, sp = 0.0;
    for (int i = tid; i < 2048; i += 1024) a += alignPart[i];
    for (int i = tid; i < JOBS_PER_MAT; i += 1024) su += Spart[i];
    for (int i = tid; i < JOBS_PER_MAT; i += 1024) sp += Spart[JOBS_PER_MAT + i];

    for (int off = 32; off; off >>= 1) {
        a  += __shfl_xor(a,  off, 64);
        su += __shfl_xor(su, off, 64);
        sp += __shfl_xor(sp, off, 64);
    }
    __shared__ double sh[3][16];
    const int lane = tid & 63, wid = tid >> 6;
    if (lane == 0) { sh[0][wid] = a; sh[1][wid] = su; sh[2][wid] = sp; }
    __syncthreads();
    if (tid == 0) {
        double A = 0.0, SU = 0.0, SP = 0.0;
        for (int i = 0; i < 16; ++i) { A += sh[0][i]; SU += sh[1][i]; SP += sh[2][i]; }
        const double Nd = 8192.0;
        const double npairs = Nd * (Nd - 1.0) * 0.5;
        const double align = A / Nd;
        const double mu = (SU - Nd) * 0.5 / npairs;
        const double mp = (SP - Nd) * 0.5 / npairs;
        const double uniform = 0.25 * (log(mu) + log(mp));
        out[0] = (float)((align + uniform) / 8192.0);
    }
}

// ---------------------------------------------------------------------------
extern "C" void kernel_launch(void* const* d_in, const int* in_sizes, int n_in,
                              void* d_out, int out_size, void* d_ws, size_t ws_size,
                              hipStream_t stream)
{
    const float* users = (const float*)d_in[0];
    const float* pos   = (const float*)d_in[1];
    float* out = (float*)d_out;

    char* ws = (char*)d_ws;
    __bf16* Uh = (__bf16*)ws;                         // 2 MiB
    __bf16* Ph = (__bf16*)(ws + 2097152);             // 2 MiB
    double* alignPart = (double*)(ws + 4194304);      // 2048 doubles
    double* Spart     = (double*)(ws + 4194304 + 16384); // 4160 doubles

    hipLaunchKernelGGL(prep_kernel, dim3(2048), dim3(256), 0, stream,
                       users, pos, Uh, Ph, alignPart);
    hipLaunchKernelGGL(gram_kernel, dim3(2 * JOBS_PER_MAT), dim3(256), 0, stream,
                       Uh, Ph, Spart);
    hipLaunchKernelGGL(finalize_kernel, dim3(1), dim3(1024), 0, stream,
                       alignPart, Spart, out);
}